// Round 16
// baseline (246.462 us; speedup 1.0000x reference)
//
#include <hip/hip_runtime.h>
#include <hip/hip_bf16.h>
#include <math.h>

#define NA 50000
#define NE 800000
#define NBIN 50176            // NA rounded to 1024*49
#define WPB 4                 // waves per block
#define NTILE 782             // 64-row tiles covering NA (dense kernels)
#define EGRID 1024            // edge blocks (4/CU)
#define NWAVES (EGRID * WPB)  // 4096 -> 12-13 dsts/wave
#define SCAT_BLKS 1024
#define RF_BLKS 391
#define PACK_BLKS 64

typedef float f32x4 __attribute__((ext_vector_type(4)));
typedef __bf16 bf16x8 __attribute__((ext_vector_type(8)));

__device__ __forceinline__ float ssp(float x) {
    float sp = (x > 15.0f) ? x : log1pf(__expf(x));
    return sp - 0.69314718f;
}

__device__ __forceinline__ uint32_t pkbf2(float a, float b) {
    union { __bf16 h[2]; uint32_t u; } x;
    x.h[0] = (__bf16)a; x.h[1] = (__bf16)b;
    return x.u;
}

// ---------------------------------------------------------------------------
// rf GEMM body, self-converting fp32 W -> hi/lo bf16 LDS (R7-proven).
// Output packed bf16.
// ---------------------------------------------------------------------------
__device__ __forceinline__ void rf_gemm_conv(const float* __restrict__ A,
                                             const float* __restrict__ W,
                                             void* __restrict__ C, int M,
                                             int blk, int gridn,
                                             __bf16* sWhi, __bf16* sWlo) {
    const int tid = threadIdx.x;
    {
        const float4* W4 = (const float4*)W;
        for (int i = tid; i < 128 * 128 / 4; i += 256) {
            float4 v = W4[i];
            #pragma unroll
            for (int q = 0; q < 4; ++q) {
                int idx = i * 4 + q;
                int k = idx >> 7, n = idx & 127;
                float x = ((const float*)&v)[q];
                __bf16 h = (__bf16)x;
                __bf16 l = (__bf16)(x - (float)h);
                int addr = n * 128 + (((k >> 3) ^ (n & 15)) << 3) + (k & 7);
                sWhi[addr] = h;
                sWlo[addr] = l;
            }
        }
    }
    __syncthreads();

    const int lane = tid & 63, w = tid >> 6;
    const int lrow = lane & 15, lgrp = lane >> 4;

    for (int base = blk * 64; base < M; base += gridn * 64) {
        const int row  = base + w * 16 + lrow;
        const int rowc = row < M ? row : M - 1;

        f32x4 acc[8];
        #pragma unroll
        for (int nt = 0; nt < 8; ++nt) acc[nt] = (f32x4){0.f, 0.f, 0.f, 0.f};

        #pragma unroll
        for (int ks = 0; ks < 4; ++ks) {
            int k0 = ks * 32 + lgrp * 8;
            float4 f0 = *(const float4*)&A[(size_t)rowc * 128 + k0];
            float4 f1 = *(const float4*)&A[(size_t)rowc * 128 + k0 + 4];
            float av[8] = {f0.x, f0.y, f0.z, f0.w, f1.x, f1.y, f1.z, f1.w};
            bf16x8 ah, al;
            #pragma unroll
            for (int j = 0; j < 8; ++j) {
                __bf16 h = (__bf16)av[j];
                ah[j] = h;
                al[j] = (__bf16)(av[j] - (float)h);
            }
            #pragma unroll
            for (int nt = 0; nt < 8; ++nt) {
                int n = nt * 16 + lrow;
                int addr = n * 128 + (((ks * 4 + lgrp) ^ (n & 15)) << 3);
                bf16x8 bh = *(const bf16x8*)&sWhi[addr];
                bf16x8 bl = *(const bf16x8*)&sWlo[addr];
                acc[nt] = __builtin_amdgcn_mfma_f32_16x16x32_bf16(ah, bh, acc[nt], 0, 0, 0);
                acc[nt] = __builtin_amdgcn_mfma_f32_16x16x32_bf16(ah, bl, acc[nt], 0, 0, 0);
                acc[nt] = __builtin_amdgcn_mfma_f32_16x16x32_bf16(al, bh, acc[nt], 0, 0, 0);
            }
        }

        const int orow = base + w * 16 + lgrp * 4;
        #pragma unroll
        for (int r = 0; r < 4; ++r) {
            if (orow + r < M) {
                #pragma unroll
                for (int nt = 0; nt < 8; ++nt) {
                    ((__hip_bfloat16*)C)[(size_t)(orow + r) * 128 + nt * 16 + lrow] =
                        __float2bfloat16(acc[nt][r]);
                }
            }
        }
    }
}

// Same body but with pre-packed hi/lo weights (straight 16B staging copies).
__device__ __forceinline__ void rf_gemm_packed(const float* __restrict__ A,
                                               const __bf16* __restrict__ pWh,
                                               const __bf16* __restrict__ pWl,
                                               void* __restrict__ C, int M,
                                               int blk, int gridn,
                                               __bf16* sWhi, __bf16* sWlo) {
    const int tid = threadIdx.x;
    {
        const uint4* ph = (const uint4*)pWh;
        const uint4* pl = (const uint4*)pWl;
        uint4* dh = (uint4*)sWhi;
        uint4* dl = (uint4*)sWlo;
        for (int i = tid; i < 2048; i += 256) { dh[i] = ph[i]; dl[i] = pl[i]; }
    }
    __syncthreads();

    const int lane = tid & 63, w = tid >> 6;
    const int lrow = lane & 15, lgrp = lane >> 4;

    for (int base = blk * 64; base < M; base += gridn * 64) {
        const int row  = base + w * 16 + lrow;
        const int rowc = row < M ? row : M - 1;

        f32x4 acc[8];
        #pragma unroll
        for (int nt = 0; nt < 8; ++nt) acc[nt] = (f32x4){0.f, 0.f, 0.f, 0.f};

        #pragma unroll
        for (int ks = 0; ks < 4; ++ks) {
            int k0 = ks * 32 + lgrp * 8;
            float4 f0 = *(const float4*)&A[(size_t)rowc * 128 + k0];
            float4 f1 = *(const float4*)&A[(size_t)rowc * 128 + k0 + 4];
            float av[8] = {f0.x, f0.y, f0.z, f0.w, f1.x, f1.y, f1.z, f1.w};
            bf16x8 ah, al;
            #pragma unroll
            for (int j = 0; j < 8; ++j) {
                __bf16 h = (__bf16)av[j];
                ah[j] = h;
                al[j] = (__bf16)(av[j] - (float)h);
            }
            #pragma unroll
            for (int nt = 0; nt < 8; ++nt) {
                int n = nt * 16 + lrow;
                int addr = n * 128 + (((ks * 4 + lgrp) ^ (n & 15)) << 3);
                bf16x8 bh = *(const bf16x8*)&sWhi[addr];
                bf16x8 bl = *(const bf16x8*)&sWlo[addr];
                acc[nt] = __builtin_amdgcn_mfma_f32_16x16x32_bf16(ah, bh, acc[nt], 0, 0, 0);
                acc[nt] = __builtin_amdgcn_mfma_f32_16x16x32_bf16(ah, bl, acc[nt], 0, 0, 0);
                acc[nt] = __builtin_amdgcn_mfma_f32_16x16x32_bf16(al, bh, acc[nt], 0, 0, 0);
            }
        }

        const int orow = base + w * 16 + lgrp * 4;
        #pragma unroll
        for (int r = 0; r < 4; ++r) {
            if (orow + r < M) {
                #pragma unroll
                for (int nt = 0; nt < 8; ++nt) {
                    ((__hip_bfloat16*)C)[(size_t)(orow + r) * 128 + nt * 16 + lrow] =
                        __float2bfloat16(acc[nt][r]);
                }
            }
        }
    }
}

// ---------------------------------------------------------------------------
// hist_rf: hist (atomic-bound) || rf-GEMM tiles [0,391) (self-converting)
//          || weight packing (64 blocks). Pack outputs are consumed only by
// LATER launches (scatter_rf / edge / dense), so no intra-kernel ordering
// is needed.
// ---------------------------------------------------------------------------
__global__ __launch_bounds__(256) void hist_rf(const int* __restrict__ a,
                                               int* __restrict__ counts,
                                               const float* __restrict__ r,
                                               const float* __restrict__ Wa,
                                               void* __restrict__ rfb,
                                               const float* __restrict__ W1,
                                               const float* __restrict__ W2,
                                               const float* __restrict__ Wf2,
                                               __bf16* __restrict__ pWaH, __bf16* __restrict__ pWaL,
                                               __bf16* __restrict__ pW1H, __bf16* __restrict__ pW1L,
                                               __bf16* __restrict__ pW2H, __bf16* __restrict__ pW2L,
                                               __bf16* __restrict__ pWf) {
    __shared__ __bf16 sWhi[128 * 128];
    __shared__ __bf16 sWlo[128 * 128];
    if (blockIdx.x < SCAT_BLKS) {
        for (int i = blockIdx.x * 256 + threadIdx.x; i < NE; i += SCAT_BLKS * 256) {
            int2 dp = ((const int2*)a)[i];
            atomicAdd(&counts[dp.x], 1);
        }
    } else if (blockIdx.x < SCAT_BLKS + RF_BLKS) {
        rf_gemm_conv(r, Wa, rfb, NA, blockIdx.x - SCAT_BLKS, 2 * RF_BLKS,
                     sWhi, sWlo);
    } else {
        const int t = (blockIdx.x - SCAT_BLKS - RF_BLKS) * 256 + threadIdx.x;
        const int stride = PACK_BLKS * 256;
        for (int i = t; i < 16384; i += stride) {
            int k = i >> 7, n = i & 127;
            int addr = n * 128 + (((k >> 3) ^ (n & 15)) << 3) + (k & 7);
            float v; __bf16 h;
            v = Wa[i]; h = (__bf16)v; pWaH[addr] = h; pWaL[addr] = (__bf16)(v - (float)h);
            v = W1[i]; h = (__bf16)v; pW1H[addr] = h; pW1L[addr] = (__bf16)(v - (float)h);
            v = W2[i]; h = (__bf16)v; pW2H[addr] = h; pW2L[addr] = (__bf16)(v - (float)h);
        }
        for (int i = t; i < 8192; i += stride) {
            int k = i >> 7, n = i & 127;
            int addr = n * 64 + (((k >> 3) ^ (n & 7)) << 3) + (k & 7);
            pWf[addr] = (__bf16)Wf2[i];
        }
    }
}

// ---------------------------------------------------------------------------
// Single-block exclusive scan over NBIN=1024*49 counts -> row_ptr, cursor.
// Two-pass per-thread (no scratch arrays), Hillis-Steele block scan.
// ---------------------------------------------------------------------------
__global__ __launch_bounds__(1024) void scan1(const int* __restrict__ counts,
                                              int* __restrict__ row_ptr,
                                              int* __restrict__ cursor) {
    __shared__ int psum[1024];
    const int t = threadIdx.x;
    const int base = t * 49;
    int s = 0;
    for (int i = 0; i < 49; ++i) s += counts[base + i];
    psum[t] = s;
    __syncthreads();
    for (int off = 1; off < 1024; off <<= 1) {
        int v = (t >= off) ? psum[t - off] : 0;
        __syncthreads();
        psum[t] += v;
        __syncthreads();
    }
    int run = psum[t] - s;   // exclusive prefix of this thread's chunk
    for (int i = 0; i < 49; ++i) {
        row_ptr[base + i] = run;
        cursor[base + i]  = run;
        run += counts[base + i];
    }
}

// ---------------------------------------------------------------------------
// scatter_rf: scatter (latency-bound) || rf-GEMM tiles [391,782) (packed Wa).
// ---------------------------------------------------------------------------
__global__ __launch_bounds__(256) void scatter_rf(const int* __restrict__ a,
                                                  const float* __restrict__ e,
                                                  int* __restrict__ cursor,
                                                  uint32_t* __restrict__ sesq,
                                                  const float* __restrict__ r,
                                                  const __bf16* __restrict__ pWaH,
                                                  const __bf16* __restrict__ pWaL,
                                                  void* __restrict__ rfb) {
    __shared__ __bf16 sWhi[128 * 128];
    __shared__ __bf16 sWlo[128 * 128];
    if (blockIdx.x < SCAT_BLKS) {
        for (int i = blockIdx.x * 256 + threadIdx.x; i < NE; i += SCAT_BLKS * 256) {
            int2 dp = ((const int2*)a)[i];
            int pos = atomicAdd(&cursor[dp.x], 1);
            uint32_t eq = (uint32_t)(e[i] * 13107.0f + 0.5f);   // 65535/5
            sesq[pos] = (eq << 16) | (uint32_t)dp.y;
        }
    } else {
        rf_gemm_packed(r, pWaH, pWaL, rfb, NA,
                       blockIdx.x - SCAT_BLKS + RF_BLKS, 2 * RF_BLKS,
                       sWhi, sWlo);
    }
}

// ---------------------------------------------------------------------------
// Fused edge pipeline. Balanced per-wave dst ranges, EGRID=1024 (4 blocks/CU).
// Per 32-edge chunk: stage sesq (register-prefetched) -> two 16-edge halves
// {gaussian (1-term bf16) -> MFMA -> bounce -> batched consume (16 gathers +
// 16 LDS reads in flight)}. Seg rows stored as packed bf16.
// g-lo term dropped: W is already 1-term bf16 here, so its rounding error
// dominates; g-lo only added sqrt(2) to an error below absmax resolution.
// ---------------------------------------------------------------------------
__global__ __launch_bounds__(256, 4) void edge_fused(const uint32_t* __restrict__ sesq,
                                                     const int* __restrict__ row_ptr,
                                                     const __bf16* __restrict__ pWf,
                                                     const float* __restrict__ bf2,
                                                     const uint32_t* __restrict__ rfb,
                                                     uint32_t* __restrict__ segb) {
    __shared__ __bf16 sWf[128 * 64];       // 16KB: Wf2^T bf16, k8 XOR swizzle
    __shared__ __bf16 sP[WPB][16 * 128];   // 4KB/wave bounce [e][f], XOR granules
    __shared__ float  sse[WPB][32];
    __shared__ int    sssrc[WPB][32];
    __shared__ int    ssrp[WPB][16];

    const int tid  = threadIdx.x;
    const int lane = tid & 63, w = tid >> 6;
    const int lrow = lane & 15, lgrp = lane >> 4;

    {
        const uint4* p = (const uint4*)pWf;
        uint4* d = (uint4*)sWf;
        for (int i = tid; i < 1024; i += 256) d[i] = p[i];
    }
    const int wi      = blockIdx.x * WPB + w;
    const int d_start = (int)(((long long)wi * NA) / NWAVES);
    const int d_end   = (int)(((long long)(wi + 1) * NA) / NWAVES);
    const int dcount  = d_end - d_start;            // 12 or 13
    if (lane <= dcount)     ssrp[w][lane] = row_ptr[d_start + lane];
    if (lane == dcount + 1) ssrp[w][lane] = 0x7FFFFFFF;
    __syncthreads();

    float bv[8];
    #pragma unroll
    for (int nt = 0; nt < 8; ++nt) bv[nt] = bf2[nt * 16 + lrow];

    const float coeff = -0.5f * (63.0f / 5.0f) * (63.0f / 5.0f);
    float* sse_w  = sse[w];
    int*   ssrc_w = sssrc[w];
    int*   srp_w  = ssrp[w];
    __bf16* myP   = sP[w];
    const uint32_t* myPu = (const uint32_t*)myP;

    const int rp0 = srp_w[0], rend = srp_w[dcount];
    int ld = 0;
    int nextb = srp_w[1];
    float racc0 = 0.0f, racc1 = 0.0f;

    // register prefetch of the first chunk's sesq
    uint32_t u_pref = 0;
    if (lane < 32 && rp0 + lane < rend) u_pref = sesq[rp0 + lane];

    for (int p = rp0; p < rend; p += 32) {
        const int cnt = (rend - p < 32) ? (rend - p) : 32;
        if (lane < 32) {
            sse_w[lane]  = (float)(u_pref >> 16) * (1.0f / 13107.0f);
            ssrc_w[lane] = (int)(u_pref & 0xFFFFu);
        }
        __builtin_amdgcn_wave_barrier();

        // prefetch NEXT chunk's sesq (1 register, in flight across the chunk)
        {
            int idx = p + 32 + lane;
            u_pref = (lane < 32 && idx < rend) ? sesq[idx] : 0u;
        }

        #pragma unroll
        for (int mt = 0; mt < 2; ++mt) {
            if (mt * 16 >= cnt) break;          // wave-uniform

            // gaussian A fragments for this 16-edge tile (1-term bf16)
            float ev = sse_w[mt * 16 + lrow];
            bf16x8 ah[2];
            #pragma unroll
            for (int ks = 0; ks < 2; ++ks) {
                #pragma unroll
                for (int j = 0; j < 8; ++j) {
                    int k = ks * 32 + lgrp * 8 + j;
                    float dd = ev - (5.0f / 63.0f) * (float)k;
                    ah[ks][j] = (__bf16)__expf(coeff * dd * dd);
                }
            }

            // filter MFMA (1-term g x bf16 W)
            f32x4 c[8];
            #pragma unroll
            for (int nt = 0; nt < 8; ++nt) c[nt] = (f32x4){0.f, 0.f, 0.f, 0.f};
            #pragma unroll
            for (int ks = 0; ks < 2; ++ks) {
                #pragma unroll
                for (int nt = 0; nt < 8; ++nt) {
                    int n = nt * 16 + lrow;
                    int addr = n * 64 + (((ks * 4 + lgrp) ^ (n & 7)) << 3);
                    bf16x8 bh = *(const bf16x8*)&sWf[addr];
                    c[nt] = __builtin_amdgcn_mfma_f32_16x16x32_bf16(ah[ks], bh, c[nt], 0, 0, 0);
                }
            }

            // bounce: bias + bf16 pack into wave-private LDS
            #pragma unroll
            for (int nt = 0; nt < 8; ++nt) {
                int f = nt * 16 + lrow;
                #pragma unroll
                for (int r = 0; r < 4; ++r) {
                    int e2 = lgrp * 4 + r;
                    float v = c[nt][r] + bv[nt];
                    myP[e2 * 128 + (((f >> 3) ^ (e2 & 7)) << 3) + (f & 7)] = (__bf16)v;
                }
            }
            __builtin_amdgcn_wave_barrier();

            // fully-batched consume: 16 bf16-rf gathers + 16 LDS reads in flight
            uint32_t rw[16];
            uint32_t uu[16];
            #pragma unroll
            for (int j = 0; j < 16; ++j) {
                int src = ssrc_w[mt * 16 + j];
                rw[j] = rfb[(size_t)src * 64 + lane];
                uu[j] = myPu[j * 64 + (((lane >> 2) ^ (j & 7)) << 2) + (lane & 3)];
            }
            #pragma unroll
            for (int j = 0; j < 16; ++j) {
                int gj = p + mt * 16 + j;
                if (gj < rend) {                       // wave-uniform
                    while (gj >= nextb) {              // wave-uniform
                        segb[(size_t)(d_start + ld) * 64 + lane] = pkbf2(racc0, racc1);
                        racc0 = 0.0f; racc1 = 0.0f;
                        ++ld;
                        nextb = srp_w[ld + 1];
                    }
                    racc0 = fmaf(__uint_as_float(rw[j] << 16),
                                 __uint_as_float(uu[j] << 16), racc0);
                    racc1 = fmaf(__uint_as_float(rw[j] & 0xFFFF0000u),
                                 __uint_as_float(uu[j] & 0xFFFF0000u), racc1);
                }
            }
            __builtin_amdgcn_wave_barrier();           // before myP reuse
        }
    }
    // flush remaining dsts (incl. trailing empty ones)
    while (ld < dcount) {
        segb[(size_t)(d_start + ld) * 64 + lane] = pkbf2(racc0, racc1);
        racc0 = 0.0f; racc1 = 0.0f;
        ++ld;
    }
}

// ---------------------------------------------------------------------------
// Dense1: y1 = ssp(seg @ W1 + b1). A = packed-bf16 seg, direct bf16x8 loads.
// ---------------------------------------------------------------------------
__global__ __launch_bounds__(256) void dense1(const uint32_t* __restrict__ segb,
                                              const __bf16* __restrict__ pW1H,
                                              const __bf16* __restrict__ pW1L,
                                              const float* __restrict__ b1,
                                              void* __restrict__ y1b) {
    __shared__ __bf16 sWhi[128 * 128];
    __shared__ __bf16 sWlo[128 * 128];
    const int tid = threadIdx.x;
    {
        const uint4* ph = (const uint4*)pW1H;
        const uint4* pl = (const uint4*)pW1L;
        uint4* dh = (uint4*)sWhi;
        uint4* dl = (uint4*)sWlo;
        for (int i = tid; i < 2048; i += 256) { dh[i] = ph[i]; dl[i] = pl[i]; }
    }
    __syncthreads();

    const int lane = tid & 63, w = tid >> 6;
    const int lrow = lane & 15, lgrp = lane >> 4;
    const __bf16* seg = (const __bf16*)segb;

    float bv[8];
    #pragma unroll
    for (int nt = 0; nt < 8; ++nt) bv[nt] = b1[nt * 16 + lrow];

    const int base = blockIdx.x * 64;
    const int row  = base + w * 16 + lrow;
    const int rowc = row < NA ? row : NA - 1;

    f32x4 acc[8];
    #pragma unroll
    for (int nt = 0; nt < 8; ++nt) acc[nt] = (f32x4){0.f, 0.f, 0.f, 0.f};

    #pragma unroll
    for (int ks = 0; ks < 4; ++ks) {
        int k0 = ks * 32 + lgrp * 8;
        bf16x8 ya = *(const bf16x8*)&seg[(size_t)rowc * 128 + k0];
        #pragma unroll
        for (int nt = 0; nt < 8; ++nt) {
            int n = nt * 16 + lrow;
            int addr = n * 128 + (((ks * 4 + lgrp) ^ (n & 15)) << 3);
            bf16x8 bh = *(const bf16x8*)&sWhi[addr];
            bf16x8 bl = *(const bf16x8*)&sWlo[addr];
            acc[nt] = __builtin_amdgcn_mfma_f32_16x16x32_bf16(ya, bh, acc[nt], 0, 0, 0);
            acc[nt] = __builtin_amdgcn_mfma_f32_16x16x32_bf16(ya, bl, acc[nt], 0, 0, 0);
        }
    }

    const int orow = base + w * 16 + lgrp * 4;
    #pragma unroll
    for (int r = 0; r < 4; ++r) {
        if (orow + r < NA) {
            #pragma unroll
            for (int nt = 0; nt < 8; ++nt) {
                float v = ssp(acc[nt][r] + bv[nt]);
                ((__hip_bfloat16*)y1b)[(size_t)(orow + r) * 128 + nt * 16 + lrow] =
                    __float2bfloat16(v);
            }
        }
    }
}

// ---------------------------------------------------------------------------
// Dense2: out = y1 @ W2 + b2.
// ---------------------------------------------------------------------------
__global__ __launch_bounds__(256) void dense2(const void* __restrict__ y1b,
                                              const __bf16* __restrict__ pW2H,
                                              const __bf16* __restrict__ pW2L,
                                              const float* __restrict__ b2,
                                              float* __restrict__ out) {
    __shared__ __bf16 sWhi[128 * 128];
    __shared__ __bf16 sWlo[128 * 128];
    const int tid = threadIdx.x;
    {
        const uint4* ph = (const uint4*)pW2H;
        const uint4* pl = (const uint4*)pW2L;
        uint4* dh = (uint4*)sWhi;
        uint4* dl = (uint4*)sWlo;
        for (int i = tid; i < 2048; i += 256) { dh[i] = ph[i]; dl[i] = pl[i]; }
    }
    __syncthreads();

    const int lane = tid & 63, w = tid >> 6;
    const int lrow = lane & 15, lgrp = lane >> 4;
    const __bf16* y1 = (const __bf16*)y1b;

    float bv[8];
    #pragma unroll
    for (int nt = 0; nt < 8; ++nt) bv[nt] = b2[nt * 16 + lrow];

    const int base = blockIdx.x * 64;
    const int row  = base + w * 16 + lrow;
    const int rowc = row < NA ? row : NA - 1;

    f32x4 acc[8];
    #pragma unroll
    for (int nt = 0; nt < 8; ++nt) acc[nt] = (f32x4){0.f, 0.f, 0.f, 0.f};

    #pragma unroll
    for (int ks = 0; ks < 4; ++ks) {
        int k0 = ks * 32 + lgrp * 8;
        bf16x8 ya = *(const bf16x8*)&y1[(size_t)rowc * 128 + k0];
        #pragma unroll
        for (int nt = 0; nt < 8; ++nt) {
            int n = nt * 16 + lrow;
            int addr = n * 128 + (((ks * 4 + lgrp) ^ (n & 15)) << 3);
            bf16x8 bh = *(const bf16x8*)&sWhi[addr];
            bf16x8 bl = *(const bf16x8*)&sWlo[addr];
            acc[nt] = __builtin_amdgcn_mfma_f32_16x16x32_bf16(ya, bh, acc[nt], 0, 0, 0);
            acc[nt] = __builtin_amdgcn_mfma_f32_16x16x32_bf16(ya, bl, acc[nt], 0, 0, 0);
        }
    }

    const int orow = base + w * 16 + lgrp * 4;
    #pragma unroll
    for (int r = 0; r < 4; ++r) {
        if (orow + r < NA) {
            #pragma unroll
            for (int nt = 0; nt < 8; ++nt) {
                out[(size_t)(orow + r) * 128 + nt * 16 + lrow] = acc[nt][r] + bv[nt];
            }
        }
    }
}

extern "C" void kernel_launch(void* const* d_in, const int* in_sizes, int n_in,
                              void* d_out, int out_size, void* d_ws, size_t ws_size,
                              hipStream_t stream) {
    const float* r   = (const float*)d_in[0];
    const float* e   = (const float*)d_in[1];
    const float* Wf2 = (const float*)d_in[2];
    const float* bf2 = (const float*)d_in[3];
    const float* Wa  = (const float*)d_in[4];
    const float* W1  = (const float*)d_in[5];
    const float* b1  = (const float*)d_in[6];
    const float* W2  = (const float*)d_in[7];
    const float* b2  = (const float*)d_in[8];
    const int*   a   = (const int*)d_in[9];

    float* out = (float*)d_out;

    // workspace layout (4B words)
    uint32_t* rfb        = (uint32_t*)d_ws;              // rf bf16   [0, 3.2M)
    uint32_t* y1b        = (uint32_t*)d_ws + 3200000;    // y1 bf16   [3.2M, 6.4M)
    int*      counts     = (int*)d_ws + 6400000;         // NBIN
    int*      row_ptr    = counts + NBIN;                // NBIN
    int*      cursor     = row_ptr + NBIN;               // NBIN
    uint32_t* sesq       = (uint32_t*)(cursor + NBIN);   // NE packed u16:u16
    __bf16*   pWaH       = (__bf16*)(sesq + NE);         // 6x16384 + 8192 bf16
    __bf16*   pWaL       = pWaH + 16384;
    __bf16*   pW1H       = pWaL + 16384;
    __bf16*   pW1L       = pW1H + 16384;
    __bf16*   pW2H       = pW1L + 16384;
    __bf16*   pW2L       = pW2H + 16384;
    __bf16*   pWf        = pW2L + 16384;

    // seg (packed bf16, 12.8MB) lives in d_out's first half; dense2 fully
    // overwrites d_out afterwards.
    uint32_t* segb = (uint32_t*)d_out;

    hipMemsetAsync(counts, 0, NBIN * sizeof(int), stream);

    // hist (atomic-bound) || rf-GEMM first half (self-conv) || weight packing
    hist_rf<<<SCAT_BLKS + RF_BLKS + PACK_BLKS, 256, 0, stream>>>(
        a, counts, r, Wa, rfb, W1, W2, Wf2,
        pWaH, pWaL, pW1H, pW1L, pW2H, pW2L, pWf);

    // single-launch exclusive scan
    scan1<<<1, 1024, 0, stream>>>(counts, row_ptr, cursor);

    // scatter (latency-bound) || rf-GEMM second half (packed Wa)
    scatter_rf<<<SCAT_BLKS + RF_BLKS, 256, 0, stream>>>(a, e, cursor, sesq,
                                                        r, pWaH, pWaL, rfb);

    // fused edge pipeline (balanced waves, 1-term g, bf16 seg out)
    edge_fused<<<EGRID, 256, 0, stream>>>(sesq, row_ptr, pWf, bf2, rfb, segb);

    // y1 = ssp(seg @ W1 + b1) (bf16 in/out); out = y1 @ W2 + b2
    dense1<<<NTILE, 256, 0, stream>>>(segb, pW1H, pW1L, b1, y1b);
    dense2<<<NTILE, 256, 0, stream>>>(y1b, pW2H, pW2L, b2, out);
}

// Round 17
// 223.712 us; speedup vs baseline: 1.1017x; 1.1017x over previous
//
#include <hip/hip_runtime.h>
#include <hip/hip_bf16.h>
#include <math.h>

#define NA 50000
#define NE 800000
#define NBIN 50176            // NA rounded to 98*512
#define NCH 98
#define WPB 4                 // waves per block
#define NTILE 782             // 64-row tiles covering NA (dense kernels)
#define EGRID 1024            // edge blocks (4/CU)
#define NWAVES (EGRID * WPB)  // 4096 -> 12-13 dsts/wave
#define SCAT_BLKS 1024
#define RF_BLKS 391

typedef float f32x4 __attribute__((ext_vector_type(4)));
typedef __bf16 bf16x8 __attribute__((ext_vector_type(8)));

__device__ __forceinline__ float ssp(float x) {
    float sp = (x > 15.0f) ? x : log1pf(__expf(x));
    return sp - 0.69314718f;
}

__device__ __forceinline__ uint32_t pkbf2(float a, float b) {
    union { __bf16 h[2]; uint32_t u; } x;
    x.h[0] = (__bf16)a; x.h[1] = (__bf16)b;
    return x.u;
}

// ---------------------------------------------------------------------------
// Pack weights once per launch into MFMA-B-fragment order (hi/lo bf16).
// ---------------------------------------------------------------------------
__global__ __launch_bounds__(256) void pack_weights(const float* __restrict__ Wa,
                                                    const float* __restrict__ W1,
                                                    const float* __restrict__ W2,
                                                    const float* __restrict__ Wf2,
                                                    __bf16* __restrict__ pWaH, __bf16* __restrict__ pWaL,
                                                    __bf16* __restrict__ pW1H, __bf16* __restrict__ pW1L,
                                                    __bf16* __restrict__ pW2H, __bf16* __restrict__ pW2L,
                                                    __bf16* __restrict__ pWf) {
    const int t = blockIdx.x * 256 + threadIdx.x;
    const int stride = gridDim.x * 256;
    for (int i = t; i < 16384; i += stride) {
        int k = i >> 7, n = i & 127;
        int addr = n * 128 + (((k >> 3) ^ (n & 15)) << 3) + (k & 7);
        float v; __bf16 h;
        v = Wa[i]; h = (__bf16)v; pWaH[addr] = h; pWaL[addr] = (__bf16)(v - (float)h);
        v = W1[i]; h = (__bf16)v; pW1H[addr] = h; pW1L[addr] = (__bf16)(v - (float)h);
        v = W2[i]; h = (__bf16)v; pW2H[addr] = h; pW2L[addr] = (__bf16)(v - (float)h);
    }
    for (int i = t; i < 8192; i += stride) {
        int k = i >> 7, n = i & 127;
        int addr = n * 64 + (((k >> 3) ^ (n & 7)) << 3) + (k & 7);
        pWf[addr] = (__bf16)Wf2[i];
    }
}

// ---------------------------------------------------------------------------
// CSR scans (R15-proven 3-launch form)
// ---------------------------------------------------------------------------
__global__ __launch_bounds__(512) void scanA(const int* __restrict__ counts,
                                             int* __restrict__ chunk_sums) {
    __shared__ int red[512];
    int t = threadIdx.x;
    red[t] = counts[blockIdx.x * 512 + t];
    __syncthreads();
    for (int off = 256; off > 0; off >>= 1) {
        if (t < off) red[t] += red[t + off];
        __syncthreads();
    }
    if (t == 0) chunk_sums[blockIdx.x] = red[0];
}

__global__ __launch_bounds__(128) void scanB(int* __restrict__ chunk_sums) {
    __shared__ int s[128];
    int t = threadIdx.x;
    int v = (t < NCH) ? chunk_sums[t] : 0;
    s[t] = v;
    __syncthreads();
    for (int off = 1; off < 128; off <<= 1) {
        int add = (t >= off) ? s[t - off] : 0;
        __syncthreads();
        s[t] += add;
        __syncthreads();
    }
    if (t < NCH) chunk_sums[t] = s[t] - v;
}

__global__ __launch_bounds__(512) void scanC(const int* __restrict__ counts,
                                             const int* __restrict__ chunk_sums,
                                             int* __restrict__ row_ptr,
                                             int* __restrict__ cursor) {
    __shared__ int s[512];
    int t = threadIdx.x;
    int i = blockIdx.x * 512 + t;
    int v = counts[i];
    s[t] = v;
    __syncthreads();
    for (int off = 1; off < 512; off <<= 1) {
        int add = (t >= off) ? s[t - off] : 0;
        __syncthreads();
        s[t] += add;
        __syncthreads();
    }
    int excl = s[t] - v + chunk_sums[blockIdx.x];
    row_ptr[i] = excl;
    cursor[i]  = excl;
}

// ---------------------------------------------------------------------------
// rf GEMM body with pre-packed weights (output packed bf16).
// ---------------------------------------------------------------------------
__device__ __forceinline__ void rf_gemm_packed(const float* __restrict__ A,
                                               const __bf16* __restrict__ pWh,
                                               const __bf16* __restrict__ pWl,
                                               void* __restrict__ C, int M,
                                               int blk, int gridn,
                                               __bf16* sWhi, __bf16* sWlo) {
    const int tid = threadIdx.x;
    {
        const uint4* ph = (const uint4*)pWh;
        const uint4* pl = (const uint4*)pWl;
        uint4* dh = (uint4*)sWhi;
        uint4* dl = (uint4*)sWlo;
        for (int i = tid; i < 2048; i += 256) { dh[i] = ph[i]; dl[i] = pl[i]; }
    }
    __syncthreads();

    const int lane = tid & 63, w = tid >> 6;
    const int lrow = lane & 15, lgrp = lane >> 4;

    for (int base = blk * 64; base < M; base += gridn * 64) {
        const int row  = base + w * 16 + lrow;
        const int rowc = row < M ? row : M - 1;

        f32x4 acc[8];
        #pragma unroll
        for (int nt = 0; nt < 8; ++nt) acc[nt] = (f32x4){0.f, 0.f, 0.f, 0.f};

        #pragma unroll
        for (int ks = 0; ks < 4; ++ks) {
            int k0 = ks * 32 + lgrp * 8;
            float4 f0 = *(const float4*)&A[(size_t)rowc * 128 + k0];
            float4 f1 = *(const float4*)&A[(size_t)rowc * 128 + k0 + 4];
            float av[8] = {f0.x, f0.y, f0.z, f0.w, f1.x, f1.y, f1.z, f1.w};
            bf16x8 ah, al;
            #pragma unroll
            for (int j = 0; j < 8; ++j) {
                __bf16 h = (__bf16)av[j];
                ah[j] = h;
                al[j] = (__bf16)(av[j] - (float)h);
            }
            #pragma unroll
            for (int nt = 0; nt < 8; ++nt) {
                int n = nt * 16 + lrow;
                int addr = n * 128 + (((ks * 4 + lgrp) ^ (n & 15)) << 3);
                bf16x8 bh = *(const bf16x8*)&sWhi[addr];
                bf16x8 bl = *(const bf16x8*)&sWlo[addr];
                acc[nt] = __builtin_amdgcn_mfma_f32_16x16x32_bf16(ah, bh, acc[nt], 0, 0, 0);
                acc[nt] = __builtin_amdgcn_mfma_f32_16x16x32_bf16(ah, bl, acc[nt], 0, 0, 0);
                acc[nt] = __builtin_amdgcn_mfma_f32_16x16x32_bf16(al, bh, acc[nt], 0, 0, 0);
            }
        }

        const int orow = base + w * 16 + lgrp * 4;
        #pragma unroll
        for (int r = 0; r < 4; ++r) {
            if (orow + r < M) {
                #pragma unroll
                for (int nt = 0; nt < 8; ++nt) {
                    ((__hip_bfloat16*)C)[(size_t)(orow + r) * 128 + nt * 16 + lrow] =
                        __float2bfloat16(acc[nt][r]);
                }
            }
        }
    }
}

// ---------------------------------------------------------------------------
// Overlap kernel 1: hist (atomic-bound) || rf-GEMM tiles [0,391)
// ---------------------------------------------------------------------------
__global__ __launch_bounds__(256) void hist_rf(const int* __restrict__ a,
                                               int* __restrict__ counts,
                                               const float* __restrict__ r,
                                               const __bf16* __restrict__ pWaH,
                                               const __bf16* __restrict__ pWaL,
                                               void* __restrict__ rfb) {
    __shared__ __bf16 sWhi[128 * 128];
    __shared__ __bf16 sWlo[128 * 128];
    if (blockIdx.x < SCAT_BLKS) {
        for (int i = blockIdx.x * 256 + threadIdx.x; i < NE; i += SCAT_BLKS * 256) {
            int2 dp = ((const int2*)a)[i];
            atomicAdd(&counts[dp.x], 1);
        }
    } else {
        rf_gemm_packed(r, pWaH, pWaL, rfb, NA, blockIdx.x - SCAT_BLKS,
                       2 * RF_BLKS, sWhi, sWlo);
    }
}

// ---------------------------------------------------------------------------
// Overlap kernel 2: scatter (latency-bound) || rf-GEMM tiles [391,782)
// ---------------------------------------------------------------------------
__global__ __launch_bounds__(256) void scatter_rf(const int* __restrict__ a,
                                                  const float* __restrict__ e,
                                                  int* __restrict__ cursor,
                                                  uint32_t* __restrict__ sesq,
                                                  const float* __restrict__ r,
                                                  const __bf16* __restrict__ pWaH,
                                                  const __bf16* __restrict__ pWaL,
                                                  void* __restrict__ rfb) {
    __shared__ __bf16 sWhi[128 * 128];
    __shared__ __bf16 sWlo[128 * 128];
    if (blockIdx.x < SCAT_BLKS) {
        for (int i = blockIdx.x * 256 + threadIdx.x; i < NE; i += SCAT_BLKS * 256) {
            int2 dp = ((const int2*)a)[i];
            int pos = atomicAdd(&cursor[dp.x], 1);
            uint32_t eq = (uint32_t)(e[i] * 13107.0f + 0.5f);   // 65535/5
            sesq[pos] = (eq << 16) | (uint32_t)dp.y;
        }
    } else {
        rf_gemm_packed(r, pWaH, pWaL, rfb, NA,
                       blockIdx.x - SCAT_BLKS + RF_BLKS, 2 * RF_BLKS,
                       sWhi, sWlo);
    }
}

// ---------------------------------------------------------------------------
// Fused edge pipeline. Balanced per-wave dst ranges, EGRID=1024 (4 blocks/CU).
// 1-term gaussian (W already bf16). segb lives in d_ws (d_out reads are the
// slow path -- R16 dense1 vs dense2 A/B evidence).
// ---------------------------------------------------------------------------
__global__ __launch_bounds__(256, 4) void edge_fused(const uint32_t* __restrict__ sesq,
                                                     const int* __restrict__ row_ptr,
                                                     const __bf16* __restrict__ pWf,
                                                     const float* __restrict__ bf2,
                                                     const uint32_t* __restrict__ rfb,
                                                     uint32_t* __restrict__ segb) {
    __shared__ __bf16 sWf[128 * 64];       // 16KB: Wf2^T bf16, k8 XOR swizzle
    __shared__ __bf16 sP[WPB][16 * 128];   // 4KB/wave bounce [e][f], XOR granules
    __shared__ float  sse[WPB][32];
    __shared__ int    sssrc[WPB][32];
    __shared__ int    ssrp[WPB][16];

    const int tid  = threadIdx.x;
    const int lane = tid & 63, w = tid >> 6;
    const int lrow = lane & 15, lgrp = lane >> 4;

    {
        const uint4* p = (const uint4*)pWf;
        uint4* d = (uint4*)sWf;
        for (int i = tid; i < 1024; i += 256) d[i] = p[i];
    }
    const int wi      = blockIdx.x * WPB + w;
    const int d_start = (int)(((long long)wi * NA) / NWAVES);
    const int d_end   = (int)(((long long)(wi + 1) * NA) / NWAVES);
    const int dcount  = d_end - d_start;            // 12 or 13
    if (lane <= dcount)     ssrp[w][lane] = row_ptr[d_start + lane];
    if (lane == dcount + 1) ssrp[w][lane] = 0x7FFFFFFF;
    __syncthreads();

    float bv[8];
    #pragma unroll
    for (int nt = 0; nt < 8; ++nt) bv[nt] = bf2[nt * 16 + lrow];

    const float coeff = -0.5f * (63.0f / 5.0f) * (63.0f / 5.0f);
    float* sse_w  = sse[w];
    int*   ssrc_w = sssrc[w];
    int*   srp_w  = ssrp[w];
    __bf16* myP   = sP[w];
    const uint32_t* myPu = (const uint32_t*)myP;

    const int rp0 = srp_w[0], rend = srp_w[dcount];
    int ld = 0;
    int nextb = srp_w[1];
    float racc0 = 0.0f, racc1 = 0.0f;

    uint32_t u_pref = 0;
    if (lane < 32 && rp0 + lane < rend) u_pref = sesq[rp0 + lane];

    for (int p = rp0; p < rend; p += 32) {
        const int cnt = (rend - p < 32) ? (rend - p) : 32;
        if (lane < 32) {
            sse_w[lane]  = (float)(u_pref >> 16) * (1.0f / 13107.0f);
            ssrc_w[lane] = (int)(u_pref & 0xFFFFu);
        }
        __builtin_amdgcn_wave_barrier();

        // prefetch NEXT chunk's sesq (1 register, in flight across the chunk)
        {
            int idx = p + 32 + lane;
            u_pref = (lane < 32 && idx < rend) ? sesq[idx] : 0u;
        }

        #pragma unroll
        for (int mt = 0; mt < 2; ++mt) {
            if (mt * 16 >= cnt) break;          // wave-uniform

            // gaussian A fragments (1-term bf16)
            float ev = sse_w[mt * 16 + lrow];
            bf16x8 ah[2];
            #pragma unroll
            for (int ks = 0; ks < 2; ++ks) {
                #pragma unroll
                for (int j = 0; j < 8; ++j) {
                    int k = ks * 32 + lgrp * 8 + j;
                    float dd = ev - (5.0f / 63.0f) * (float)k;
                    ah[ks][j] = (__bf16)__expf(coeff * dd * dd);
                }
            }

            // filter MFMA (1-term)
            f32x4 c[8];
            #pragma unroll
            for (int nt = 0; nt < 8; ++nt) c[nt] = (f32x4){0.f, 0.f, 0.f, 0.f};
            #pragma unroll
            for (int ks = 0; ks < 2; ++ks) {
                #pragma unroll
                for (int nt = 0; nt < 8; ++nt) {
                    int n = nt * 16 + lrow;
                    int addr = n * 64 + (((ks * 4 + lgrp) ^ (n & 7)) << 3);
                    bf16x8 bh = *(const bf16x8*)&sWf[addr];
                    c[nt] = __builtin_amdgcn_mfma_f32_16x16x32_bf16(ah[ks], bh, c[nt], 0, 0, 0);
                }
            }

            // bounce: bias + bf16 pack into wave-private LDS
            #pragma unroll
            for (int nt = 0; nt < 8; ++nt) {
                int f = nt * 16 + lrow;
                #pragma unroll
                for (int r = 0; r < 4; ++r) {
                    int e2 = lgrp * 4 + r;
                    float v = c[nt][r] + bv[nt];
                    myP[e2 * 128 + (((f >> 3) ^ (e2 & 7)) << 3) + (f & 7)] = (__bf16)v;
                }
            }
            __builtin_amdgcn_wave_barrier();

            // fully-batched consume: 16 bf16-rf gathers + 16 LDS reads in flight
            uint32_t rw[16];
            uint32_t uu[16];
            #pragma unroll
            for (int j = 0; j < 16; ++j) {
                int src = ssrc_w[mt * 16 + j];
                rw[j] = rfb[(size_t)src * 64 + lane];
                uu[j] = myPu[j * 64 + (((lane >> 2) ^ (j & 7)) << 2) + (lane & 3)];
            }
            #pragma unroll
            for (int j = 0; j < 16; ++j) {
                int gj = p + mt * 16 + j;
                if (gj < rend) {                       // wave-uniform
                    while (gj >= nextb) {              // wave-uniform
                        segb[(size_t)(d_start + ld) * 64 + lane] = pkbf2(racc0, racc1);
                        racc0 = 0.0f; racc1 = 0.0f;
                        ++ld;
                        nextb = srp_w[ld + 1];
                    }
                    racc0 = fmaf(__uint_as_float(rw[j] << 16),
                                 __uint_as_float(uu[j] << 16), racc0);
                    racc1 = fmaf(__uint_as_float(rw[j] & 0xFFFF0000u),
                                 __uint_as_float(uu[j] & 0xFFFF0000u), racc1);
                }
            }
            __builtin_amdgcn_wave_barrier();           // before myP reuse
        }
    }
    while (ld < dcount) {
        segb[(size_t)(d_start + ld) * 64 + lane] = pkbf2(racc0, racc1);
        racc0 = 0.0f; racc1 = 0.0f;
        ++ld;
    }
}

// ---------------------------------------------------------------------------
// Dense1: y1 = ssp(seg @ W1 + b1). A = packed-bf16 seg (ws), direct bf16x8.
// ---------------------------------------------------------------------------
__global__ __launch_bounds__(256) void dense1(const uint32_t* __restrict__ segb,
                                              const __bf16* __restrict__ pW1H,
                                              const __bf16* __restrict__ pW1L,
                                              const float* __restrict__ b1,
                                              void* __restrict__ y1b) {
    __shared__ __bf16 sWhi[128 * 128];
    __shared__ __bf16 sWlo[128 * 128];
    const int tid = threadIdx.x;
    {
        const uint4* ph = (const uint4*)pW1H;
        const uint4* pl = (const uint4*)pW1L;
        uint4* dh = (uint4*)sWhi;
        uint4* dl = (uint4*)sWlo;
        for (int i = tid; i < 2048; i += 256) { dh[i] = ph[i]; dl[i] = pl[i]; }
    }
    __syncthreads();

    const int lane = tid & 63, w = tid >> 6;
    const int lrow = lane & 15, lgrp = lane >> 4;
    const __bf16* seg = (const __bf16*)segb;

    float bv[8];
    #pragma unroll
    for (int nt = 0; nt < 8; ++nt) bv[nt] = b1[nt * 16 + lrow];

    const int base = blockIdx.x * 64;
    const int row  = base + w * 16 + lrow;
    const int rowc = row < NA ? row : NA - 1;

    f32x4 acc[8];
    #pragma unroll
    for (int nt = 0; nt < 8; ++nt) acc[nt] = (f32x4){0.f, 0.f, 0.f, 0.f};

    #pragma unroll
    for (int ks = 0; ks < 4; ++ks) {
        int k0 = ks * 32 + lgrp * 8;
        bf16x8 ya = *(const bf16x8*)&seg[(size_t)rowc * 128 + k0];
        #pragma unroll
        for (int nt = 0; nt < 8; ++nt) {
            int n = nt * 16 + lrow;
            int addr = n * 128 + (((ks * 4 + lgrp) ^ (n & 15)) << 3);
            bf16x8 bh = *(const bf16x8*)&sWhi[addr];
            bf16x8 bl = *(const bf16x8*)&sWlo[addr];
            acc[nt] = __builtin_amdgcn_mfma_f32_16x16x32_bf16(ya, bh, acc[nt], 0, 0, 0);
            acc[nt] = __builtin_amdgcn_mfma_f32_16x16x32_bf16(ya, bl, acc[nt], 0, 0, 0);
        }
    }

    const int orow = base + w * 16 + lgrp * 4;
    #pragma unroll
    for (int r = 0; r < 4; ++r) {
        if (orow + r < NA) {
            #pragma unroll
            for (int nt = 0; nt < 8; ++nt) {
                float v = ssp(acc[nt][r] + bv[nt]);
                ((__hip_bfloat16*)y1b)[(size_t)(orow + r) * 128 + nt * 16 + lrow] =
                    __float2bfloat16(v);
            }
        }
    }
}

// ---------------------------------------------------------------------------
// Dense2: out = y1 @ W2 + b2. Only writer of d_out.
// ---------------------------------------------------------------------------
__global__ __launch_bounds__(256) void dense2(const void* __restrict__ y1b,
                                              const __bf16* __restrict__ pW2H,
                                              const __bf16* __restrict__ pW2L,
                                              const float* __restrict__ b2,
                                              float* __restrict__ out) {
    __shared__ __bf16 sWhi[128 * 128];
    __shared__ __bf16 sWlo[128 * 128];
    const int tid = threadIdx.x;
    {
        const uint4* ph = (const uint4*)pW2H;
        const uint4* pl = (const uint4*)pW2L;
        uint4* dh = (uint4*)sWhi;
        uint4* dl = (uint4*)sWlo;
        for (int i = tid; i < 2048; i += 256) { dh[i] = ph[i]; dl[i] = pl[i]; }
    }
    __syncthreads();

    const int lane = tid & 63, w = tid >> 6;
    const int lrow = lane & 15, lgrp = lane >> 4;
    const __bf16* y1 = (const __bf16*)y1b;

    float bv[8];
    #pragma unroll
    for (int nt = 0; nt < 8; ++nt) bv[nt] = b2[nt * 16 + lrow];

    const int base = blockIdx.x * 64;
    const int row  = base + w * 16 + lrow;
    const int rowc = row < NA ? row : NA - 1;

    f32x4 acc[8];
    #pragma unroll
    for (int nt = 0; nt < 8; ++nt) acc[nt] = (f32x4){0.f, 0.f, 0.f, 0.f};

    #pragma unroll
    for (int ks = 0; ks < 4; ++ks) {
        int k0 = ks * 32 + lgrp * 8;
        bf16x8 ya = *(const bf16x8*)&y1[(size_t)rowc * 128 + k0];
        #pragma unroll
        for (int nt = 0; nt < 8; ++nt) {
            int n = nt * 16 + lrow;
            int addr = n * 128 + (((ks * 4 + lgrp) ^ (n & 15)) << 3);
            bf16x8 bh = *(const bf16x8*)&sWhi[addr];
            bf16x8 bl = *(const bf16x8*)&sWlo[addr];
            acc[nt] = __builtin_amdgcn_mfma_f32_16x16x32_bf16(ya, bh, acc[nt], 0, 0, 0);
            acc[nt] = __builtin_amdgcn_mfma_f32_16x16x32_bf16(ya, bl, acc[nt], 0, 0, 0);
        }
    }

    const int orow = base + w * 16 + lgrp * 4;
    #pragma unroll
    for (int r = 0; r < 4; ++r) {
        if (orow + r < NA) {
            #pragma unroll
            for (int nt = 0; nt < 8; ++nt) {
                out[(size_t)(orow + r) * 128 + nt * 16 + lrow] = acc[nt][r] + bv[nt];
            }
        }
    }
}

extern "C" void kernel_launch(void* const* d_in, const int* in_sizes, int n_in,
                              void* d_out, int out_size, void* d_ws, size_t ws_size,
                              hipStream_t stream) {
    const float* r   = (const float*)d_in[0];
    const float* e   = (const float*)d_in[1];
    const float* Wf2 = (const float*)d_in[2];
    const float* bf2 = (const float*)d_in[3];
    const float* Wa  = (const float*)d_in[4];
    const float* W1  = (const float*)d_in[5];
    const float* b1  = (const float*)d_in[6];
    const float* W2  = (const float*)d_in[7];
    const float* b2  = (const float*)d_in[8];
    const int*   a   = (const int*)d_in[9];

    float* out = (float*)d_out;

    // workspace layout (4B words) -- segb now in ws (d_out reads are slow)
    uint32_t* rfb        = (uint32_t*)d_ws;              // rf bf16   [0, 3.2M)
    uint32_t* y1b        = (uint32_t*)d_ws + 3200000;    // y1 bf16   [3.2M, 6.4M)
    uint32_t* segb       = (uint32_t*)d_ws + 6400000;    // seg bf16  [6.4M, 9.6M)
    int*      counts     = (int*)d_ws + 9600000;         // NBIN
    int*      row_ptr    = counts + NBIN;                // NBIN
    int*      cursor     = row_ptr + NBIN;               // NBIN
    int*      chunk_sums = cursor + NBIN;                // 128
    uint32_t* sesq       = (uint32_t*)(chunk_sums + 128);// NE packed u16:u16
    __bf16*   pWaH       = (__bf16*)(sesq + NE);         // 6x16384 + 8192 bf16
    __bf16*   pWaL       = pWaH + 16384;
    __bf16*   pW1H       = pWaL + 16384;
    __bf16*   pW1L       = pW1H + 16384;
    __bf16*   pW2H       = pW1L + 16384;
    __bf16*   pW2L       = pW2H + 16384;
    __bf16*   pWf        = pW2L + 16384;

    hipMemsetAsync(counts, 0, NBIN * sizeof(int), stream);
    pack_weights<<<64, 256, 0, stream>>>(Wa, W1, W2, Wf2,
                                         pWaH, pWaL, pW1H, pW1L, pW2H, pW2L, pWf);

    // hist (atomic-bound) || rf-GEMM first half
    hist_rf<<<SCAT_BLKS + RF_BLKS, 256, 0, stream>>>(a, counts, r, pWaH, pWaL, rfb);
    scanA<<<NCH, 512, 0, stream>>>(counts, chunk_sums);
    scanB<<<1, 128, 0, stream>>>(chunk_sums);
    scanC<<<NCH, 512, 0, stream>>>(counts, chunk_sums, row_ptr, cursor);
    // scatter (latency-bound) || rf-GEMM second half
    scatter_rf<<<SCAT_BLKS + RF_BLKS, 256, 0, stream>>>(a, e, cursor, sesq,
                                                        r, pWaH, pWaL, rfb);

    // fused edge pipeline (balanced waves, 1-term g, segb in ws)
    edge_fused<<<EGRID, 256, 0, stream>>>(sesq, row_ptr, pWf, bf2, rfb, segb);

    // y1 = ssp(seg @ W1 + b1); out = y1 @ W2 + b2 (d_out written once, here)
    dense1<<<NTILE, 256, 0, stream>>>(segb, pW1H, pW1L, b1, y1b);
    dense2<<<NTILE, 256, 0, stream>>>(y1b, pW2H, pW2L, b2, out);
}